// Round 1
// 554.087 us; speedup vs baseline: 1.0655x; 1.0655x over previous
//
#include <hip/hip_runtime.h>
#include <cstdint>
#include <cstddef>

#define E_ 8
#define D_ 768
#define F_ 3072
#define N_ 16384
#define CAP_ 2560   // int(1.25 * 16384 / 8)
#define NCHUNK_ (N_ / 256)   // 64

typedef __attribute__((ext_vector_type(8))) short bf16x8;
typedef __attribute__((ext_vector_type(4))) float f32x4;

__device__ __forceinline__ unsigned short f2bf(float f) {
  unsigned u = __float_as_uint(f);
  u += 0x7fffu + ((u >> 16) & 1u);   // round-to-nearest-even
  return (unsigned short)(u >> 16);
}

__device__ __forceinline__ void gload16(const void* g, void* l) {
  __builtin_amdgcn_global_load_lds(
      (const __attribute__((address_space(1))) void*)g,
      (__attribute__((address_space(3))) void*)l, 16, 0, 0);
}

// ---------------- transpose + cast weights: src [E][R][C] fp32 -> dst [E][C][R] bf16 ----------------
__global__ void tcast_kernel(const float* __restrict__ src, unsigned short* __restrict__ dst,
                             int R, int C) {
  __shared__ float tile[64][65];
  int e = blockIdx.z;
  const float* s = src + (size_t)e * R * C;
  unsigned short* d = dst + (size_t)e * R * C;
  int c0 = blockIdx.x * 64, r0 = blockIdx.y * 64;
  int tx = threadIdx.x, ty = threadIdx.y;
  #pragma unroll
  for (int rr = ty; rr < 64; rr += 8) {
    tile[rr][tx]      = s[(size_t)(r0 + rr) * C + c0 + tx];
    tile[rr][tx + 32] = s[(size_t)(r0 + rr) * C + c0 + tx + 32];
  }
  __syncthreads();
  #pragma unroll
  for (int cc = ty; cc < 64; cc += 8) {
    ushort2 o;
    o.x = f2bf(tile[2 * tx][cc]);       // LDS stride 2*65 between lanes -> 2-way, free
    o.y = f2bf(tile[2 * tx + 1][cc]);
    *(ushort2*)&d[(size_t)(c0 + cc) * R + r0 + 2 * tx] = o;
  }
}

// ---------------- router (fused x->bf16 cast): NO global atomics ----------------
__global__ __launch_bounds__(256) void router_kernel(
    const float* __restrict__ x, const float* __restrict__ sw, const float* __restrict__ sb,
    int* __restrict__ route, float* __restrict__ prob,
    unsigned short* __restrict__ xb) {
  __shared__ float wl[E_ * D_];   // wl[e][d], stride-1 in d
  int tid = threadIdx.x;
  #pragma unroll
  for (int ee = 0; ee < E_; ++ee)
    for (int dd = tid; dd < D_; dd += 256)
      wl[ee * D_ + dd] = sw[dd * E_ + ee];
  __syncthreads();
  int wave = tid >> 6, lane = tid & 63;
  int tbase = blockIdx.x * 16 + wave * 4;
  #pragma unroll
  for (int tt = 0; tt < 4; ++tt) {
    int t = tbase + tt;
    const float* xp = x + (size_t)t * D_;
    unsigned short* xbp = xb + (size_t)t * D_;
    float acc[E_];
    #pragma unroll
    for (int e = 0; e < E_; ++e) acc[e] = 0.f;
    #pragma unroll
    for (int r = 0; r < D_ / 64; ++r) {
      int dd = r * 64 + lane;
      float xv = xp[dd];
      xbp[dd] = f2bf(xv);               // fused cast
      #pragma unroll
      for (int e = 0; e < E_; ++e) acc[e] += xv * wl[e * D_ + dd];
    }
    #pragma unroll
    for (int e = 0; e < E_; ++e) {
      #pragma unroll
      for (int o = 32; o > 0; o >>= 1) acc[e] += __shfl_xor(acc[e], o);
    }
    if (lane == 0) {
      float mx = -1e30f; int arg = 0;
      #pragma unroll
      for (int e = 0; e < E_; ++e) {
        float l = acc[e] + sb[e];
        acc[e] = l;
        if (l > mx) { mx = l; arg = e; }   // strict > : first index on ties (np argmax)
      }
      float s = 0.f;
      #pragma unroll
      for (int e = 0; e < E_; ++e) s += expf(acc[e] - mx);
      route[t] = arg;
      prob[t] = 1.f / s;                   // = max softmax prob
    }
  }
}

// ---------------- per-chunk histogram (LDS atomics only) ----------------
__global__ void hist_kernel(const int* __restrict__ route, int* __restrict__ chunk_hist) {
  __shared__ int h[E_];
  int tid = threadIdx.x;
  if (tid < E_) h[tid] = 0;
  __syncthreads();
  atomicAdd(&h[route[blockIdx.x * 256 + tid]], 1);
  __syncthreads();
  if (tid < E_) chunk_hist[blockIdx.x * E_ + tid] = h[tid];
}

// ---------------- exclusive scan over chunks per expert (single tiny block) ----------------
__global__ void scan_kernel(const int* __restrict__ chunk_hist, int* __restrict__ chunk_off,
                            int* __restrict__ counts) {
  __shared__ int h[NCHUNK_ * E_];
  int tid = threadIdx.x;
  h[tid] = chunk_hist[tid];          // 512 threads, 512 values
  __syncthreads();
  if (tid < E_) {
    int run = 0;
    for (int c = 0; c < NCHUNK_; ++c) {
      chunk_off[c * E_ + tid] = run;
      run += h[c * E_ + tid];
    }
    counts[tid] = run;
  }
}

// ---------------- slot assignment: deterministic, atomic-free ----------------
__global__ void assign_kernel(const int* __restrict__ route, const float* __restrict__ prob,
                              const int* __restrict__ counts, const int* __restrict__ chunk_off,
                              int* __restrict__ tok_list, int* __restrict__ slot) {
  __shared__ int rt[256];
  int tid = threadIdx.x;
  int i = blockIdx.x * 256 + tid;
  int e = route[i];
  rt[tid] = e;
  __syncthreads();
  int r = 0;
  for (int j = 0; j < tid; ++j) r += (rt[j] == e) ? 1 : 0;   // broadcast reads, conflict-free
  int c = counts[e];
  int s; bool keep;
  if (c <= CAP_) {
    s = chunk_off[blockIdx.x * E_ + e] + r;   // bijective slot in [0, c)
    keep = true;
  } else {
    // exact rank: tokens sorted by desc prob, stable by index (matches lexsort)
    float p = prob[i];
    int rr = 0;
    for (int j = 0; j < N_; ++j) {
      if (route[j] == e) {
        float pj = prob[j];
        rr += (pj > p || (pj == p && j < i)) ? 1 : 0;
      }
    }
    s = rr; keep = (rr < CAP_);
  }
  if (keep) tok_list[e * CAP_ + s] = i;
  slot[i] = keep ? s : -1;
}

// =====================================================================================
// 256x256-tile BK=64 grouped GEMMs, 8 waves (2M x 4N), double-buffered 128 KiB LDS.
// Pipeline (T3-minimum): stage K-tile t+1 at TOP of iter t; one __syncthreads()
//   (= vmcnt(0)+barrier) per K-tile at the bottom -> loads have a full compute
//   phase of latency cover. Race-free: stage targets the buffer whose reads all
//   completed before the previous barrier.
// T2 swizzle (rule 21: both-sides-or-neither with global_load_lds):
//   LDS rows are 64 bf16 = 128 B = 8 x 16 B chunks. LDS(row, c) holds global
//   chunk c ^ (row&7); applied by permuting the per-lane GLOBAL source chunk
//   (dest stays linear: wave base + lane*16) and XOR-ing the fragment-read chunk.
//   Fragment reads (16 rows x same chunk) then spread over all 8 slots -> 2-way
//   residual (free) instead of 8-way.
// T5: setprio(1) around the MFMA cluster.
// =====================================================================================

// ---------------- GEMM1: h[e][m][f] = gelu( x[tok] @ w1[e] + b1[e] ) ----------------
__global__ __launch_bounds__(512, 2) void gemm1_kernel(
    const unsigned short* __restrict__ xb, const unsigned short* __restrict__ w1t,
    const float* __restrict__ b1, const int* __restrict__ tok_list,
    const int* __restrict__ counts, unsigned short* __restrict__ hb) {
  int e = blockIdx.z;
  int Me = counts[e] < CAP_ ? counts[e] : CAP_;
  int m0 = blockIdx.x * 256;
  if (m0 >= Me) return;
  int n0 = blockIdx.y * 256;
  __shared__ unsigned short sm[65536];   // [buf][A 16384 | B 16384] shorts = 128 KiB
  int tid = threadIdx.x, lane = tid & 63, w = tid >> 6;
  // staging geometry: round ar covers rows [ar*64, ar*64+64); wave w rows w*8+(lane>>3)
  int srow = w * 8 + (lane >> 3);
  int schunk = (lane & 7) ^ (lane >> 3);          // source chunk = chunk_P ^ (row&7)
  unsigned dstA = (unsigned)(w * 512);            // shorts; + ar*4096 (+16384 for B, +32768 for buf1)
  // A sources: gathered token rows (clamped; rows >= Me discarded at store)
  const char* sA[4];
  #pragma unroll
  for (int ar = 0; ar < 4; ++ar) {
    int rw = m0 + ar * 64 + srow;
    if (rw > Me - 1) rw = Me - 1;
    int tok = tok_list[e * CAP_ + rw];
    sA[ar] = (const char*)(xb + (size_t)tok * D_) + schunk * 16;
  }
  const char* sB = (const char*)(w1t + ((size_t)e * F_ + n0 + srow) * D_) + schunk * 16;
  const size_t BR = (size_t)64 * D_ * 2;          // B round stride (64 rows)
  // fragment addressing
  int fr = lane & 15, q = lane >> 4;
  int wm = (w >> 2) * 128, wn = (w & 3) * 64;
  f32x4 acc[8][4] = {};

  // prologue: stage tile 0 -> buf 0
  #pragma unroll
  for (int ar = 0; ar < 4; ++ar) {
    gload16(sA[ar], sm + ar * 4096 + dstA);
    gload16(sB + ar * BR, sm + 16384 + ar * 4096 + dstA);
  }
  __syncthreads();

  const int NT = D_ / 64;   // 12
  for (int kt = 0; kt < NT; ++kt) {
    int cb = kt & 1;
    if (kt + 1 < NT) {                 // stage tile kt+1 into other buffer (issue-early)
      int ob = cb ^ 1;
      size_t ko = (size_t)(kt + 1) * 128;
      #pragma unroll
      for (int ar = 0; ar < 4; ++ar) {
        gload16(sA[ar] + ko, sm + ob * 32768 + ar * 4096 + dstA);
        gload16(sB + ar * BR + ko, sm + ob * 32768 + 16384 + ar * 4096 + dstA);
      }
    }
    const unsigned short* A  = sm + cb * 32768;
    const unsigned short* Bm = A + 16384;
    #pragma unroll
    for (int kh = 0; kh < 2; ++kh) {
      bf16x8 bfr[4];
      #pragma unroll
      for (int j = 0; j < 4; ++j) {
        int row = wn + j * 16 + fr;
        int pc = (kh * 4 + q) ^ (fr & 7);
        bfr[j] = *(const bf16x8*)(Bm + row * 64 + pc * 8);
      }
      __builtin_amdgcn_s_setprio(1);
      #pragma unroll
      for (int i = 0; i < 8; ++i) {
        int row = wm + i * 16 + fr;
        int pc = (kh * 4 + q) ^ (fr & 7);
        bf16x8 afr = *(const bf16x8*)(A + row * 64 + pc * 8);
        #pragma unroll
        for (int j = 0; j < 4; ++j)
          acc[i][j] = __builtin_amdgcn_mfma_f32_16x16x32_bf16(afr, bfr[j], acc[i][j], 0, 0, 0);
      }
      __builtin_amdgcn_s_setprio(0);
    }
    __syncthreads();                   // vmcnt(0)+lgkmcnt(0)+barrier: next tile ready
  }

  int q4 = q * 4;
  #pragma unroll
  for (int i = 0; i < 8; ++i) {
    #pragma unroll
    for (int j = 0; j < 4; ++j) {
      int col = n0 + wn + j * 16 + fr;
      float bias = b1[e * F_ + col];
      #pragma unroll
      for (int r = 0; r < 4; ++r) {
        int row = m0 + wm + i * 16 + q4 + r;
        if (row < Me) {
          float v = acc[i][j][r] + bias;
          v = 0.5f * v * (1.f + erff(v * 0.70710678118654752f));   // exact GELU
          hb[((size_t)e * CAP_ + row) * F_ + col] = f2bf(v);
        }
      }
    }
  }
}

// ---------------- GEMM2: out[tok] = (h[e] @ w2[e] + b2[e]) * prob[tok] ----------------
__global__ __launch_bounds__(512, 2) void gemm2_kernel(
    const unsigned short* __restrict__ hb, const unsigned short* __restrict__ w2t,
    const float* __restrict__ b2, const int* __restrict__ tok_list,
    const int* __restrict__ counts, const float* __restrict__ prob,
    float* __restrict__ out) {
  int e = blockIdx.z;
  int Me = counts[e] < CAP_ ? counts[e] : CAP_;
  int m0 = blockIdx.x * 256;
  if (m0 >= Me) return;
  int n0 = blockIdx.y * 256;
  __shared__ unsigned short sm[65536];
  int tid = threadIdx.x, lane = tid & 63, w = tid >> 6;
  int srow = w * 8 + (lane >> 3);
  int schunk = (lane & 7) ^ (lane >> 3);
  unsigned dstA = (unsigned)(w * 512);
  // A: dense hb rows (poison rows >= Me are finite bf16 and discarded at store)
  const char* sA[4];
  #pragma unroll
  for (int ar = 0; ar < 4; ++ar)
    sA[ar] = (const char*)(hb + ((size_t)e * CAP_ + m0 + ar * 64 + srow) * F_) + schunk * 16;
  const char* sB = (const char*)(w2t + ((size_t)e * D_ + n0 + srow) * F_) + schunk * 16;
  const size_t BR = (size_t)64 * F_ * 2;
  int fr = lane & 15, q = lane >> 4;
  int wm = (w >> 2) * 128, wn = (w & 3) * 64;
  f32x4 acc[8][4] = {};

  #pragma unroll
  for (int ar = 0; ar < 4; ++ar) {
    gload16(sA[ar], sm + ar * 4096 + dstA);
    gload16(sB + ar * BR, sm + 16384 + ar * 4096 + dstA);
  }
  __syncthreads();

  const int NT = F_ / 64;   // 48
  for (int kt = 0; kt < NT; ++kt) {
    int cb = kt & 1;
    if (kt + 1 < NT) {
      int ob = cb ^ 1;
      size_t ko = (size_t)(kt + 1) * 128;
      #pragma unroll
      for (int ar = 0; ar < 4; ++ar) {
        gload16(sA[ar] + ko, sm + ob * 32768 + ar * 4096 + dstA);
        gload16(sB + ar * BR + ko, sm + ob * 32768 + 16384 + ar * 4096 + dstA);
      }
    }
    const unsigned short* A  = sm + cb * 32768;
    const unsigned short* Bm = A + 16384;
    #pragma unroll
    for (int kh = 0; kh < 2; ++kh) {
      bf16x8 bfr[4];
      #pragma unroll
      for (int j = 0; j < 4; ++j) {
        int row = wn + j * 16 + fr;
        int pc = (kh * 4 + q) ^ (fr & 7);
        bfr[j] = *(const bf16x8*)(Bm + row * 64 + pc * 8);
      }
      __builtin_amdgcn_s_setprio(1);
      #pragma unroll
      for (int i = 0; i < 8; ++i) {
        int row = wm + i * 16 + fr;
        int pc = (kh * 4 + q) ^ (fr & 7);
        bf16x8 afr = *(const bf16x8*)(A + row * 64 + pc * 8);
        #pragma unroll
        for (int j = 0; j < 4; ++j)
          acc[i][j] = __builtin_amdgcn_mfma_f32_16x16x32_bf16(afr, bfr[j], acc[i][j], 0, 0, 0);
      }
      __builtin_amdgcn_s_setprio(0);
    }
    __syncthreads();
  }

  int q4 = q * 4;
  #pragma unroll
  for (int i = 0; i < 8; ++i) {
    #pragma unroll
    for (int r = 0; r < 4; ++r) {
      int row = m0 + wm + i * 16 + q4 + r;
      if (row < Me) {
        int tok = tok_list[e * CAP_ + row];
        float pm = prob[tok];
        #pragma unroll
        for (int j = 0; j < 4; ++j) {
          int col = n0 + wn + j * 16 + fr;
          float v = (acc[i][j][r] + b2[e * D_ + col]) * pm;
          out[(size_t)tok * D_ + col] = v;
        }
      }
    }
  }
}

// ---------------- passthrough for dropped tokens ----------------
__global__ void passthrough_kernel(const float* __restrict__ x, const float* __restrict__ prob,
                                   const int* __restrict__ slot, float* __restrict__ out) {
  int t = blockIdx.x;
  if (slot[t] >= 0) return;
  float p = prob[t];
  for (int d = threadIdx.x; d < D_; d += 256)
    out[(size_t)t * D_ + d] = x[(size_t)t * D_ + d] * p;
}

extern "C" void kernel_launch(void* const* d_in, const int* in_sizes, int n_in,
                              void* d_out, int out_size, void* d_ws, size_t ws_size,
                              hipStream_t stream) {
  const float* x  = (const float*)d_in[0];
  const float* sw = (const float*)d_in[1];
  const float* sb = (const float*)d_in[2];
  const float* w1 = (const float*)d_in[3];
  const float* b1 = (const float*)d_in[4];
  const float* w2 = (const float*)d_in[5];
  const float* b2 = (const float*)d_in[6];
  float* out = (float*)d_out;
  (void)in_sizes; (void)n_in; (void)out_size; (void)ws_size;

  char* ws = (char*)d_ws;
  size_t off = 0;
  auto alloc = [&](size_t bytes) {
    char* p = ws + off;
    off = (off + bytes + 255) & ~(size_t)255;
    return p;
  };
  int* counts     = (int*)alloc(32 * sizeof(int));
  int* chunk_hist = (int*)alloc((size_t)NCHUNK_ * E_ * sizeof(int));
  int* chunk_off  = (int*)alloc((size_t)NCHUNK_ * E_ * sizeof(int));
  int* tok_list   = (int*)alloc((size_t)E_ * CAP_ * sizeof(int));
  int* route      = (int*)alloc((size_t)N_ * 4);
  float* prob     = (float*)alloc((size_t)N_ * 4);
  int* slot       = (int*)alloc((size_t)N_ * 4);
  unsigned short* xb  = (unsigned short*)alloc((size_t)N_ * D_ * 2);
  unsigned short* w1t = (unsigned short*)alloc((size_t)E_ * D_ * F_ * 2);
  unsigned short* w2t = (unsigned short*)alloc((size_t)E_ * D_ * F_ * 2);
  unsigned short* hb  = (unsigned short*)alloc((size_t)E_ * CAP_ * F_ * 2);

  dim3 tb(32, 8);
  tcast_kernel<<<dim3(F_ / 64, D_ / 64, E_), tb, 0, stream>>>(w1, w1t, D_, F_);
  tcast_kernel<<<dim3(D_ / 64, F_ / 64, E_), tb, 0, stream>>>(w2, w2t, F_, D_);
  router_kernel<<<N_ / 16, 256, 0, stream>>>(x, sw, sb, route, prob, xb);
  hist_kernel<<<NCHUNK_, 256, 0, stream>>>(route, chunk_hist);
  scan_kernel<<<1, NCHUNK_ * E_, 0, stream>>>(chunk_hist, chunk_off, counts);
  assign_kernel<<<NCHUNK_, 256, 0, stream>>>(route, prob, counts, chunk_off, tok_list, slot);
  gemm1_kernel<<<dim3(CAP_ / 256, F_ / 256, E_), 512, 0, stream>>>(xb, w1t, b1, tok_list, counts, hb);
  gemm2_kernel<<<dim3(CAP_ / 256, D_ / 256, E_), 512, 0, stream>>>(hb, w2t, b2, tok_list, counts, prob, out);
  passthrough_kernel<<<N_, 256, 0, stream>>>(x, prob, slot, out);
}